// Round 2
// baseline (11858.266 us; speedup 1.0000x reference)
//
#include <hip/hip_runtime.h>

typedef __attribute__((ext_vector_type(8))) short short8;
typedef __attribute__((ext_vector_type(4))) float f32x4;

#define NN 4096     // neurons
#define NB 32       // batch
#define TSTEPS 291  // t = 0..290 (last record at t=290; steps 291..299 unused)
#define FF_T 300    // ff_input time stride
#define NBLK 256    // grid size == CU count; 1 block/CU capacity guaranteed

// float -> bf16 round-to-nearest-even, as raw bits in a short
__device__ __forceinline__ short f2bf(float x) {
    unsigned u = __builtin_bit_cast(unsigned, x);
    unsigned r = (u + 0x7FFFu + ((u >> 16) & 1u)) >> 16;
    return (short)r;
}

// Device-scope grid barrier: flat counter, monotone target per epoch.
// Release fence flushes dirty L2 (agent scope, cross-XCD); acquire fence
// invalidates L1/stale L2 before reading other XCDs' rates.
__device__ __forceinline__ void grid_barrier(int* cnt, int target) {
    __builtin_amdgcn_fence(__ATOMIC_RELEASE, "agent");
    __syncthreads();
    if (threadIdx.x == 0) {
        __hip_atomic_fetch_add(cnt, 1, __ATOMIC_RELEASE, __HIP_MEMORY_SCOPE_AGENT);
        while (__hip_atomic_load(cnt, __ATOMIC_ACQUIRE, __HIP_MEMORY_SCOPE_AGENT) < target) {
            __builtin_amdgcn_s_sleep(4);
        }
    }
    __syncthreads();
    __builtin_amdgcn_fence(__ATOMIC_ACQUIRE, "agent");
}

// Persistent kernel. One WG per CU; WG c owns output columns [16c,16c+16)
// for all 32 batches. W lives in registers as MFMA B-frags (128 VGPRs/wave)
// for the whole simulation. rates exchanged via a double-buffered bf16
// global buffer; one software grid barrier per step.
__global__ __launch_bounds__(256, 1)
void rnn_kernel(const float* __restrict__ W,
                const float* __restrict__ ff,
                const float* __restrict__ rec0,
                float* __restrict__ out,
                int* __restrict__ cnt,
                short* __restrict__ ratesA,
                short* __restrict__ ratesB)
{
    const int tid  = threadIdx.x;
    const int wave = tid >> 6;
    const int lane = tid & 63;
    const int n0   = blockIdx.x * 16;

    __shared__ float part[4][32][17];   // per-wave K-partials (padded)
    __shared__ float recS[32][16];      // rec state (fp32)
    __shared__ float rateS[32][16];     // rates state (fp32)
    __shared__ float accS[32][16];      // window accumulator

    // ---- init: rec0, rates0 = relu(ff[:,0] + rec0), window acc = 0
    for (int e = tid; e < 512; e += 256) {
        const int b = e >> 4, nl = e & 15;
        const float rc = rec0[b * NN + n0 + nl];
        const float f0 = ff[((size_t)b * FF_T) * NN + n0 + nl];
        const float r0 = fmaxf(f0 + rc, 0.0f);
        recS[b][nl]  = rc;
        rateS[b][nl] = r0;
        accS[b][nl]  = 0.0f;
        ratesA[b * NN + n0 + nl] = f2bf(r0);
    }

    // ---- load W (fp32 [k][n]) into registers as bf16 B-fragments.
    // wave w covers k in [w*1024, (w+1)*1024); for K-step kt, lane holds
    // B[k = w*1024 + kt*32 + (lane>>4)*8 + j][n = n0 + (lane&15)], j=0..7
    short8 Bfr[32];
    {
        const int ncol  = n0 + (lane & 15);
        const size_t kb = (size_t)(wave * 1024 + ((lane >> 4) * 8));
        #pragma unroll
        for (int kt = 0; kt < 32; ++kt) {
            short8 f;
            #pragma unroll
            for (int j = 0; j < 8; ++j) {
                f[j] = f2bf(W[(kb + (size_t)kt * 32 + j) * NN + ncol]);
            }
            Bfr[kt] = f;
        }
    }

    int epoch = 1;
    grid_barrier(cnt, NBLK * epoch);   // rates0 visible everywhere

    // A-frag: lane reads rates[m][k], m = lane&15 (+16 for 2nd M-tile),
    // k = wave*1024 + kt*32 + (lane>>4)*8 + j  (j contiguous -> short8 load)
    const int arow     = lane & 15;
    const int acolbase = wave * 1024 + ((lane >> 4) * 8);

    for (int t = 0; t < TSTEPS; ++t) {
        const short* __restrict__ rbuf = (t & 1) ? ratesB : ratesA;
        short* __restrict__ wbuf       = (t & 1) ? ratesA : ratesB;

        f32x4 acc0 = {0.f, 0.f, 0.f, 0.f};
        f32x4 acc1 = {0.f, 0.f, 0.f, 0.f};
        const short* pa0 = rbuf + (size_t)arow * NN + acolbase;
        const short* pa1 = pa0 + 16 * NN;
        #pragma unroll
        for (int kt = 0; kt < 32; ++kt) {
            short8 a0 = *(const short8*)(pa0 + kt * 32);
            short8 a1 = *(const short8*)(pa1 + kt * 32);
            acc0 = __builtin_amdgcn_mfma_f32_16x16x32_bf16(a0, Bfr[kt], acc0, 0, 0, 0);
            acc1 = __builtin_amdgcn_mfma_f32_16x16x32_bf16(a1, Bfr[kt], acc1, 0, 0, 0);
        }

        // C/D layout: col = lane&15, row = (lane>>4)*4 + reg  [m89-verified]
        const int prow = (lane >> 4) * 4;
        const int pcol = lane & 15;
        #pragma unroll
        for (int r = 0; r < 4; ++r) {
            part[wave][prow + r][pcol]      = acc0[r];
            part[wave][16 + prow + r][pcol] = acc1[r];
        }
        __syncthreads();

        // fused update: reduce K-partials, rec/rate decay, window accumulate,
        // publish new rates (bf16) for next step
        for (int e = tid; e < 512; e += 256) {
            const int b = e >> 4, nl = e & 15;
            const float hidden = part[0][b][nl] + part[1][b][nl]
                               + part[2][b][nl] + part[3][b][nl];
            const float rc  = recS[b][nl] * 0.95122945f + hidden * 0.05f; // exp(-dt/tau_syn), dt/tau_syn
            const float net = ff[((size_t)b * FF_T + t) * NN + n0 + nl] + rc;
            const float rt  = rateS[b][nl] * 0.90483743f + fmaxf(net, 0.0f) * 0.1f; // exp(-dt/tau), dt/tau
            recS[b][nl]  = rc;
            rateS[b][nl] = rt;
            accS[b][nl]  = (t >= 90) ? (accS[b][nl] + rt) : 0.0f;
            wbuf[b * NN + n0 + nl] = f2bf(rt);
        }

        // record: windows end at t = 100,110,...,290 (first window = 11 terms /10,
        // matching cs[100]-cs[89] in the reference)
        if (t >= 100 && (t % 10) == 0) {
            const int w = (t - 100) / 10;
            for (int e = tid; e < 512; e += 256) {
                const int b = e >> 4, nl = e & 15;
                out[((size_t)b * 20 + w) * NN + n0 + nl] = accS[b][nl] * 0.1f;
                accS[b][nl] = 0.0f;
            }
        }

        epoch++;
        grid_barrier(cnt, NBLK * epoch);  // new rates globally visible; orders LDS reuse
    }
}

extern "C" void kernel_launch(void* const* d_in, const int* in_sizes, int n_in,
                              void* d_out, int out_size, void* d_ws, size_t ws_size,
                              hipStream_t stream)
{
    const float* W    = (const float*)d_in[0];   // Wab_T [4096,4096] fp32, row-major [k][n]
    const float* ff   = (const float*)d_in[1];   // [32,300,4096] fp32
    const float* rec0 = (const float*)d_in[2];   // [32,4096] fp32
    float* out = (float*)d_out;                  // [32,20,4096] fp32

    int*   cnt    = (int*)d_ws;                  // barrier counter (zeroed below)
    short* ratesA = (short*)((char*)d_ws + 256); // bf16 rates double buffer
    short* ratesB = ratesA + NB * NN;

    hipMemsetAsync(d_ws, 0, 256, stream);        // graph-capturable memset node

    rnn_kernel<<<dim3(NBLK), dim3(256), 0, stream>>>(W, ff, rec0, out, cnt, ratesA, ratesB);
}

// Round 3
// 8102.218 us; speedup vs baseline: 1.4636x; 1.4636x over previous
//
#include <hip/hip_runtime.h>

typedef __attribute__((ext_vector_type(8))) short short8;
typedef __attribute__((ext_vector_type(4))) float f32x4;

#define NN 4096     // neurons
#define NB 32       // batch
#define TSTEPS 291  // t = 0..290 (last record at t=290; steps 291..299 unused)
#define FF_T 300    // ff_input time stride
#define NBLK 256    // grid size == CU count; 1 block/CU capacity guaranteed

// float -> bf16 round-to-nearest-even, raw bits in a short
__device__ __forceinline__ short f2bf(float x) {
    unsigned u = __builtin_bit_cast(unsigned, x);
    unsigned r = (u + 0x7FFFu + ((u >> 16) & 1u)) >> 16;
    return (short)r;
}
__device__ __forceinline__ unsigned pack2bf(float x0, float x1) {
    return ((unsigned)(unsigned short)f2bf(x0))
         | (((unsigned)(unsigned short)f2bf(x1)) << 16);
}

// Flag-array grid barrier: zero atomic contention, and — critically — the
// poll uses RELAXED loads (no buffer_inv per iteration; R2's ACQUIRE-in-loop
// was issuing a full L2 invalidate per spin). Exactly one wbl2 (release) and
// one inv (acquire) per block per step.
__device__ __forceinline__ void grid_barrier(int* __restrict__ flags, int epoch) {
    const int tid = threadIdx.x;
    __syncthreads();   // drains vmcnt(0): all this block's stores are in L2
    if (tid == 0) {
        __builtin_amdgcn_fence(__ATOMIC_RELEASE, "agent");  // wbl2: dirty L2 -> coherent point
        __hip_atomic_store(&flags[blockIdx.x], epoch,
                           __ATOMIC_RELAXED, __HIP_MEMORY_SCOPE_AGENT);
    }
    // thread t polls block t's flag; relaxed agent loads bypass stale caches
    while (__hip_atomic_load(&flags[tid], __ATOMIC_RELAXED,
                             __HIP_MEMORY_SCOPE_AGENT) < epoch) {
        __builtin_amdgcn_s_sleep(2);
    }
    __syncthreads();
    __builtin_amdgcn_fence(__ATOMIC_ACQUIRE, "agent");      // single inv: drop stale lines
}

// Persistent kernel. One WG per CU; WG c owns output columns [16c,16c+16)
// for all 32 batches. W lives in registers as MFMA B-frags (128 VGPRs/wave)
// for the whole run. Per-neuron fp32 state (rec, rate, window-acc) lives in
// registers: thread owns elements (b = tid>>3, n = n0 + (tid&7)*2 + {0,1}).
__global__ __launch_bounds__(256, 1)
void rnn_kernel(const float* __restrict__ W,
                const float* __restrict__ ff,
                const float* __restrict__ rec0p,
                float* __restrict__ out,
                int* __restrict__ flags,
                short* __restrict__ ratesA,
                short* __restrict__ ratesB)
{
    const int tid  = threadIdx.x;
    const int wave = tid >> 6;
    const int lane = tid & 63;
    const int n0   = blockIdx.x * 16;

    __shared__ float part[4][32][18];   // per-wave K-partials; stride 18 keeps
                                        // float2 reads aligned, 2-way banks (free)

    // per-thread state element indices
    const int sb  = tid >> 3;           // batch 0..31
    const int nl0 = (tid & 7) * 2;      // even neuron-local index 0..14

    // ---- init: rec0, rates0 = relu(ff[:,0] + rec0)
    const size_t sidx = (size_t)sb * NN + n0 + nl0;
    float rc0 = rec0p[sidx], rc1 = rec0p[sidx + 1];
    const float* ff0p = ff + ((size_t)sb * FF_T) * NN + n0 + nl0;
    float rt0 = fmaxf(ff0p[0] + rc0, 0.0f);
    float rt1 = fmaxf(ff0p[1] + rc1, 0.0f);
    float ac0 = 0.0f, ac1 = 0.0f;
    *(unsigned*)(ratesA + sidx) = pack2bf(rt0, rt1);

    // ---- W (fp32 [k][n]) -> register bf16 B-fragments.
    // wave w covers k in [w*1024, (w+1)*1024); for K-step kt, lane holds
    // B[k = w*1024 + kt*32 + (lane>>4)*8 + j][n = n0 + (lane&15)], j=0..7
    short8 Bfr[32];
    {
        const int ncol  = n0 + (lane & 15);
        const size_t kb = (size_t)(wave * 1024 + ((lane >> 4) * 8));
        #pragma unroll
        for (int kt = 0; kt < 32; ++kt) {
            short8 f;
            #pragma unroll
            for (int j = 0; j < 8; ++j) {
                f[j] = f2bf(W[(kb + (size_t)kt * 32 + j) * NN + ncol]);
            }
            Bfr[kt] = f;
        }
    }

    int epoch = 1;
    grid_barrier(flags, epoch);   // rates0 globally visible

    // A-frag: lane reads rates[m][k], m = lane&15 (+16 for 2nd M-tile),
    // k = wave*1024 + kt*32 + (lane>>4)*8 + j (contiguous -> short8 load)
    const int arow     = lane & 15;
    const int acolbase = wave * 1024 + ((lane >> 4) * 8);

    for (int t = 0; t < TSTEPS; ++t) {
        const short* __restrict__ rbuf = (t & 1) ? ratesB : ratesA;
        short* __restrict__ wbuf       = (t & 1) ? ratesA : ratesB;

        // prefetch this step's ff early to overlap with the MFMA loop
        const float* ffp = ff + ((size_t)sb * FF_T + t) * NN + n0 + nl0;
        const float ffv0 = ffp[0];
        const float ffv1 = ffp[1];

        f32x4 acc0 = {0.f, 0.f, 0.f, 0.f};
        f32x4 acc1 = {0.f, 0.f, 0.f, 0.f};
        const short* pa0 = rbuf + (size_t)arow * NN + acolbase;
        const short* pa1 = pa0 + 16 * NN;
        #pragma unroll
        for (int kt = 0; kt < 32; ++kt) {
            short8 a0 = *(const short8*)(pa0 + kt * 32);
            short8 a1 = *(const short8*)(pa1 + kt * 32);
            acc0 = __builtin_amdgcn_mfma_f32_16x16x32_bf16(a0, Bfr[kt], acc0, 0, 0, 0);
            acc1 = __builtin_amdgcn_mfma_f32_16x16x32_bf16(a1, Bfr[kt], acc1, 0, 0, 0);
        }

        // C/D layout: col = lane&15, row = (lane>>4)*4 + reg  [m89-verified]
        const int prow = (lane >> 4) * 4;
        const int pcol = lane & 15;
        #pragma unroll
        for (int r = 0; r < 4; ++r) {
            part[wave][prow + r][pcol]      = acc0[r];
            part[wave][16 + prow + r][pcol] = acc1[r];
        }
        __syncthreads();

        // fused update on this thread's two elements (state in registers)
        const float h0 = part[0][sb][nl0] + part[1][sb][nl0]
                       + part[2][sb][nl0] + part[3][sb][nl0];
        const float h1 = part[0][sb][nl0+1] + part[1][sb][nl0+1]
                       + part[2][sb][nl0+1] + part[3][sb][nl0+1];
        rc0 = rc0 * 0.95122945f + h0 * 0.05f;   // exp(-dt/tau_syn), dt/tau_syn
        rc1 = rc1 * 0.95122945f + h1 * 0.05f;
        rt0 = rt0 * 0.90483743f + fmaxf(ffv0 + rc0, 0.0f) * 0.1f; // exp(-dt/tau), dt/tau
        rt1 = rt1 * 0.90483743f + fmaxf(ffv1 + rc1, 0.0f) * 0.1f;
        if (t >= 90) { ac0 += rt0; ac1 += rt1; }
        *(unsigned*)(wbuf + sidx) = pack2bf(rt0, rt1);

        // record: windows end at t = 100,110,...,290 (first window = 11 terms /10,
        // matching cs[100]-cs[89] in the reference)
        if (t >= 100 && (t % 10) == 0) {
            const int w = (t - 100) / 10;
            float* op = out + ((size_t)sb * 20 + w) * NN + n0 + nl0;
            op[0] = ac0 * 0.1f;
            op[1] = ac1 * 0.1f;
            ac0 = 0.0f; ac1 = 0.0f;
        }

        epoch++;
        grid_barrier(flags, epoch);  // publishes new rates; orders LDS reuse
    }
}

extern "C" void kernel_launch(void* const* d_in, const int* in_sizes, int n_in,
                              void* d_out, int out_size, void* d_ws, size_t ws_size,
                              hipStream_t stream)
{
    const float* W    = (const float*)d_in[0];   // Wab_T [4096,4096] fp32, row-major [k][n]
    const float* ff   = (const float*)d_in[1];   // [32,300,4096] fp32
    const float* rec0 = (const float*)d_in[2];   // [32,4096] fp32
    float* out = (float*)d_out;                  // [32,20,4096] fp32

    int*   flags  = (int*)d_ws;                   // 256 arrival flags (zeroed below)
    short* ratesA = (short*)((char*)d_ws + 4096); // bf16 rates double buffer
    short* ratesB = ratesA + NB * NN;

    hipMemsetAsync(d_ws, 0, 4096, stream);        // graph-capturable memset node

    rnn_kernel<<<dim3(NBLK), dim3(256), 0, stream>>>(W, ff, rec0, out, flags, ratesA, ratesB);
}

// Round 4
// 5056.584 us; speedup vs baseline: 2.3451x; 1.6023x over previous
//
#include <hip/hip_runtime.h>

typedef __attribute__((ext_vector_type(8))) short short8;
typedef __attribute__((ext_vector_type(4))) float f32x4;

#define NN 4096     // neurons
#define NB 32       // batch
#define TSTEPS 291  // t = 0..290 (last record at t=290; steps 291..299 unused)
#define FF_T 300    // ff_input time stride
#define NBLK 256    // grid size == CU count; 1 block/CU capacity guaranteed

// float -> bf16 round-to-nearest-even, raw bits in a short
__device__ __forceinline__ short f2bf(float x) {
    unsigned u = __builtin_bit_cast(unsigned, x);
    unsigned r = (u + 0x7FFFu + ((u >> 16) & 1u)) >> 16;
    return (short)r;
}
__device__ __forceinline__ unsigned pack2bf(float x0, float x1) {
    return ((unsigned)(unsigned short)f2bf(x0))
         | (((unsigned)(unsigned short)f2bf(x1)) << 16);
}

// Coherent-point store/load (lower to global_store/load_dword sc1 — bypass
// L2, visible cross-XCD without any wbl2 fence).
__device__ __forceinline__ void st_coh(int* p, int v) {
    __hip_atomic_store(p, v, __ATOMIC_RELAXED, __HIP_MEMORY_SCOPE_AGENT);
}
__device__ __forceinline__ int ld_coh(const int* p) {
    return __hip_atomic_load(p, __ATOMIC_RELAXED, __HIP_MEMORY_SCOPE_AGENT);
}

// Two-hop grid barrier. No release fence (rates are published via sc1
// write-through stores; __syncthreads drains each wave's vmcnt before the
// arrival store). Block 0 aggregates 256 arrival flags into one `go` word;
// all other blocks poll that single word with ONE lane. Exactly one
// acquire fence (buffer_inv) per block per step, which keeps normal cached
// A-loads correct while preserving per-XCD L2 broadcast amplification.
__device__ __forceinline__ void grid_barrier(int* __restrict__ flags,
                                             int* __restrict__ go, int epoch) {
    __syncthreads();   // all waves: s_waitcnt vmcnt(0) — rates stores at L3
    if (threadIdx.x == 0)
        st_coh(&flags[blockIdx.x], epoch);
    if (blockIdx.x == 0) {
        // master: thread t waits for block t's arrival, then publish go
        while (ld_coh(&flags[threadIdx.x]) < epoch)
            __builtin_amdgcn_s_sleep(1);
        __syncthreads();
        if (threadIdx.x == 0)
            st_coh(go, epoch);
    }
    if (threadIdx.x == 0) {
        while (ld_coh(go) < epoch)
            __builtin_amdgcn_s_sleep(2);
    }
    __syncthreads();
    __builtin_amdgcn_fence(__ATOMIC_ACQUIRE, "agent");  // buffer_inv only
}

// Persistent kernel. One WG per CU; WG c owns output columns [16c,16c+16)
// for all 32 batches. W lives in registers as MFMA B-frags (128 VGPRs/wave)
// for the whole run. Per-neuron fp32 state (rec, rate, window-acc) in
// registers: thread owns elements (b = tid>>3, n = n0 + (tid&7)*2 + {0,1}).
__global__ __launch_bounds__(256, 1)
void rnn_kernel(const float* __restrict__ W,
                const float* __restrict__ ff,
                const float* __restrict__ rec0p,
                float* __restrict__ out,
                int* __restrict__ flags,
                int* __restrict__ go,
                short* __restrict__ ratesA,
                short* __restrict__ ratesB)
{
    const int tid  = threadIdx.x;
    const int wave = tid >> 6;
    const int lane = tid & 63;
    const int n0   = blockIdx.x * 16;

    __shared__ float part[4][32][18];   // per-wave K-partials (padded)

    // per-thread state element indices
    const int sb  = tid >> 3;           // batch 0..31
    const int nl0 = (tid & 7) * 2;      // even neuron-local index 0..14

    // ---- init: rec0, rates0 = relu(ff[:,0] + rec0)
    const size_t sidx = (size_t)sb * NN + n0 + nl0;
    float rc0 = rec0p[sidx], rc1 = rec0p[sidx + 1];
    const float* ff0p = ff + ((size_t)sb * FF_T) * NN + n0 + nl0;
    float rt0 = fmaxf(ff0p[0] + rc0, 0.0f);
    float rt1 = fmaxf(ff0p[1] + rc1, 0.0f);
    float ac0 = 0.0f, ac1 = 0.0f;
    st_coh((int*)(ratesA + sidx), (int)pack2bf(rt0, rt1));

    // ---- W (fp32 [k][n]) -> register bf16 B-fragments.
    // wave w covers k in [w*1024, (w+1)*1024); for K-step kt, lane holds
    // B[k = w*1024 + kt*32 + (lane>>4)*8 + j][n = n0 + (lane&15)], j=0..7
    short8 Bfr[32];
    {
        const int ncol  = n0 + (lane & 15);
        const size_t kb = (size_t)(wave * 1024 + ((lane >> 4) * 8));
        #pragma unroll
        for (int kt = 0; kt < 32; ++kt) {
            short8 f;
            #pragma unroll
            for (int j = 0; j < 8; ++j) {
                f[j] = f2bf(W[(kb + (size_t)kt * 32 + j) * NN + ncol]);
            }
            Bfr[kt] = f;
        }
    }

    int epoch = 1;
    grid_barrier(flags, go, epoch);   // rates0 globally visible

    // A-frag: lane reads rates[m][k], m = lane&15 (+16 for 2nd M-tile),
    // k = wave*1024 + kt*32 + (lane>>4)*8 + j (contiguous -> short8 load).
    // Normal cached loads: served from per-XCD L2 after one L3 fill.
    const int arow     = lane & 15;
    const int acolbase = wave * 1024 + ((lane >> 4) * 8);

    for (int t = 0; t < TSTEPS; ++t) {
        const short* __restrict__ rbuf = (t & 1) ? ratesB : ratesA;
        short* __restrict__ wbuf       = (t & 1) ? ratesA : ratesB;

        // prefetch this step's ff early to overlap with the MFMA loop
        const float* ffp = ff + ((size_t)sb * FF_T + t) * NN + n0 + nl0;
        const float ffv0 = ffp[0];
        const float ffv1 = ffp[1];

        f32x4 acc0 = {0.f, 0.f, 0.f, 0.f};
        f32x4 acc1 = {0.f, 0.f, 0.f, 0.f};
        const short* pa0 = rbuf + (size_t)arow * NN + acolbase;
        const short* pa1 = pa0 + 16 * NN;
        #pragma unroll
        for (int kt = 0; kt < 32; ++kt) {
            short8 a0 = *(const short8*)(pa0 + kt * 32);
            short8 a1 = *(const short8*)(pa1 + kt * 32);
            acc0 = __builtin_amdgcn_mfma_f32_16x16x32_bf16(a0, Bfr[kt], acc0, 0, 0, 0);
            acc1 = __builtin_amdgcn_mfma_f32_16x16x32_bf16(a1, Bfr[kt], acc1, 0, 0, 0);
        }

        // C/D layout: col = lane&15, row = (lane>>4)*4 + reg  [m89-verified]
        const int prow = (lane >> 4) * 4;
        const int pcol = lane & 15;
        #pragma unroll
        for (int r = 0; r < 4; ++r) {
            part[wave][prow + r][pcol]      = acc0[r];
            part[wave][16 + prow + r][pcol] = acc1[r];
        }
        __syncthreads();

        // fused update on this thread's two elements (state in registers)
        const float h0 = part[0][sb][nl0] + part[1][sb][nl0]
                       + part[2][sb][nl0] + part[3][sb][nl0];
        const float h1 = part[0][sb][nl0+1] + part[1][sb][nl0+1]
                       + part[2][sb][nl0+1] + part[3][sb][nl0+1];
        rc0 = rc0 * 0.95122945f + h0 * 0.05f;   // exp(-dt/tau_syn), dt/tau_syn
        rc1 = rc1 * 0.95122945f + h1 * 0.05f;
        rt0 = rt0 * 0.90483743f + fmaxf(ffv0 + rc0, 0.0f) * 0.1f; // exp(-dt/tau), dt/tau
        rt1 = rt1 * 0.90483743f + fmaxf(ffv1 + rc1, 0.0f) * 0.1f;
        if (t >= 90) { ac0 += rt0; ac1 += rt1; }
        // publish new rates straight to the coherence point (sc1 store);
        // no wbl2 needed at the barrier.
        st_coh((int*)(wbuf + sidx), (int)pack2bf(rt0, rt1));

        // record: windows end at t = 100,110,...,290 (first window = 11 terms
        // /10, matching cs[100]-cs[89] in the reference)
        if (t >= 100 && (t % 10) == 0) {
            const int w = (t - 100) / 10;
            float* op = out + ((size_t)sb * 20 + w) * NN + n0 + nl0;
            op[0] = ac0 * 0.1f;
            op[1] = ac1 * 0.1f;
            ac0 = 0.0f; ac1 = 0.0f;
        }

        epoch++;
        grid_barrier(flags, go, epoch);  // publishes new rates; orders LDS reuse
    }
}

extern "C" void kernel_launch(void* const* d_in, const int* in_sizes, int n_in,
                              void* d_out, int out_size, void* d_ws, size_t ws_size,
                              hipStream_t stream)
{
    const float* W    = (const float*)d_in[0];   // Wab_T [4096,4096] fp32, row-major [k][n]
    const float* ff   = (const float*)d_in[1];   // [32,300,4096] fp32
    const float* rec0 = (const float*)d_in[2];   // [32,4096] fp32
    float* out = (float*)d_out;                  // [32,20,4096] fp32

    int*   flags  = (int*)d_ws;                   // 256 arrival flags
    int*   go     = (int*)d_ws + 512;             // single release word
    short* ratesA = (short*)((char*)d_ws + 4096); // bf16 rates double buffer
    short* ratesB = ratesA + NB * NN;

    hipMemsetAsync(d_ws, 0, 4096, stream);        // graph-capturable memset node

    rnn_kernel<<<dim3(NBLK), dim3(256), 0, stream>>>(W, ff, rec0, out,
                                                     flags, go, ratesA, ratesB);
}